// Round 2
// baseline (587.631 us; speedup 1.0000x reference)
//
#include <hip/hip_runtime.h>
#include <math.h>

// Problem constants
#define D_FEAT   128
#define O_SIZE   256
#define N_NEUR   1024

// Intermediate u[256][128] lives in module-owned device memory, NOT d_ws.
// (Round-1 post-mortem: writing 128 KiB to d_ws corrupted adjacent harness
// buffers -> first launch passed, later launches stably diverged. ws_size
// was evidently < 128 KiB.)
__device__ __align__(16) float g_u[O_SIZE * D_FEAT];

// Fast, safe tanh: error ~1e-7 absolute, no inf/nan for any input.
__device__ __forceinline__ float tanh_fast(float x) {
    x = fminf(fmaxf(x, -20.f), 20.f);
    float e = __expf(2.f * x);
    return (e - 1.f) / (e + 1.f);
}

// ---------------------------------------------------------------------------
// Kernel B: v0 preamble + 256-step sequential chain. ONE workgroup.
//   v0[j]  = ss0 * sx[j];  sx[j] = sum_i x[i,j];  ss0 = dot(sum_k pos_tail[k,:], pos_head[0,:])
//   u_t    = v_t @ W[t]           (128x128 matvec)
//   v_{t+1}[j] = tanh(a[t, t+1] * u_t[j])
// Writes u[256][128] to g_u.
// ---------------------------------------------------------------------------
__global__ __launch_bounds__(1024) void chain_kernel(
    const float* __restrict__ x,
    const float* __restrict__ pos_head,
    const float* __restrict__ pos_tail,
    const float* __restrict__ W,
    const float* __restrict__ a)
{
    __shared__ float v_lds[D_FEAT];
    __shared__ float psum[32][D_FEAT];
    __shared__ float red[64];

    const int tid = threadIdx.x;

    // ---- preamble: v0 ----
    float sx = 0.f;
    if (tid < 128) {
        #pragma unroll 8
        for (int i = 0; i < 256; ++i) sx += x[i * 128 + tid];
    } else if (tid < 192) {
        const int d = tid - 128;
        float pt = 0.f;
        #pragma unroll 8
        for (int k = 0; k < 256; ++k) pt += pos_tail[k * 64 + d];
        red[d] = pt * pos_head[d];   // pos_head row 0
    }
    __syncthreads();
    if (tid < 128) {
        float ss0 = 0.f;
        #pragma unroll
        for (int d = 0; d < 64; ++d) ss0 += red[d];
        v_lds[tid] = ss0 * sx;
    }
    __syncthreads();

    // ---- chain ----
    // Thread (h, jg): h = m-block (4 rows), jg = column-group (4 cols, float4).
    const int jg = tid & 31;
    const int h  = tid >> 5;
    const float4* Wv = (const float4*)W;   // (t, m, col4) -> t*4096 + m*32 + col4

    float4 wc[4], wn[4];
    #pragma unroll
    for (int i = 0; i < 4; ++i)
        wc[i] = Wv[(h * 4 + i) * 32 + jg];           // W[0]

    for (int t = 0; t < O_SIZE; ++t) {
        // prefetch next step's W slice (overlaps this step's compute+barriers)
        if (t + 1 < O_SIZE) {
            #pragma unroll
            for (int i = 0; i < 4; ++i)
                wn[i] = Wv[(size_t)(t + 1) * 4096 + (h * 4 + i) * 32 + jg];
        }

        float4 acc = {0.f, 0.f, 0.f, 0.f};
        #pragma unroll
        for (int i = 0; i < 4; ++i) {
            const float vm = v_lds[h * 4 + i];
            acc.x += vm * wc[i].x;
            acc.y += vm * wc[i].y;
            acc.z += vm * wc[i].z;
            acc.w += vm * wc[i].w;
        }
        ((float4*)psum[h])[jg] = acc;
        __syncthreads();

        if (tid < 128) {
            float uj = 0.f;
            #pragma unroll
            for (int hh = 0; hh < 32; ++hh) uj += psum[hh][tid];
            g_u[t * 128 + tid] = uj;
            const float c = a[t * N_NEUR + t + 1];   // a[t, t+1]
            v_lds[tid] = tanh_fast(c * uj);
        }
        __syncthreads();

        #pragma unroll
        for (int i = 0; i < 4; ++i) wc[i] = wn[i];
    }
}

// ---------------------------------------------------------------------------
// Kernel C: out[t,l,j] = tanh(a[t,l] * u[t,j]), t<256, l<1024, j<128.
// One thread -> one float4 (4 j's). 33.5M elems, write-bandwidth bound.
// ---------------------------------------------------------------------------
__global__ __launch_bounds__(256) void out_kernel(
    const float* __restrict__ a,
    float* __restrict__ out)
{
    const long gid = (long)blockIdx.x * 256 + threadIdx.x;
    const long row = gid >> 5;            // t*1024 + l  (0..262143)
    const int  jq  = (int)(gid & 31);     // float4 index within the 128-col row
    const int  t   = (int)(row >> 10);

    const float  s  = a[row];             // a[t*1024 + l] == a[row] for t<256
    const float4 u4 = ((const float4*)g_u)[t * 32 + jq];

    float4 r;
    r.x = tanh_fast(s * u4.x);
    r.y = tanh_fast(s * u4.y);
    r.z = tanh_fast(s * u4.z);
    r.w = tanh_fast(s * u4.w);

    ((float4*)out)[row * 32 + jq] = r;
}

// ---------------------------------------------------------------------------
extern "C" void kernel_launch(void* const* d_in, const int* in_sizes, int n_in,
                              void* d_out, int out_size, void* d_ws, size_t ws_size,
                              hipStream_t stream)
{
    const float* x        = (const float*)d_in[0];
    const float* pos_head = (const float*)d_in[1];
    const float* pos_tail = (const float*)d_in[2];
    const float* W        = (const float*)d_in[3];
    const float* a        = (const float*)d_in[4];
    float*       out      = (float*)d_out;

    hipLaunchKernelGGL(chain_kernel, dim3(1), dim3(1024), 0, stream,
                       x, pos_head, pos_tail, W, a);

    // 262144 rows * 32 float4/row / (256 threads) = 32768 blocks
    hipLaunchKernelGGL(out_kernel, dim3(32768), dim3(256), 0, stream,
                       a, out);
}

// Round 3
// 423.449 us; speedup vs baseline: 1.3877x; 1.3877x over previous
//
#include <hip/hip_runtime.h>
#include <math.h>

// Problem constants
#define D_FEAT   128
#define O_SIZE   256
#define N_NEUR   1024
#define STEPS_PER_WG 4
#define N_WG     (O_SIZE / STEPS_PER_WG)   // 64

typedef unsigned long long ull;

// Module-owned device memory (NOT d_ws — round-1 post-mortem: d_ws too small,
// OOB writes corrupted harness pristine buffers).
__device__ __align__(16) float g_u[O_SIZE * D_FEAT];
// Baton channel: one 128-entry slot per handoff. Each entry packs
// (tag << 32) | float_bits(v_j). Data travels inside the atomic -> no fences.
__device__ ull g_chan[N_WG][D_FEAT];

#define TAG_INVALID 0xFFFFFFFFu

// Fast, safe tanh: |err| ~1e-7, no inf/nan for any input.
__device__ __forceinline__ float tanh_fast(float x) {
    x = fminf(fmaxf(x, -20.f), 20.f);
    float e = __expf(2.f * x);
    return (e - 1.f) * __builtin_amdgcn_rcpf(e + 1.f);
}

// ---------------------------------------------------------------------------
// Init kernel (1 WG, 1024 threads):
//  1) invalidate baton slots 1..N_WG-1 (kills stale tags from previous replay)
//  2) compute v0[j] = ss0 * sx[j] and publish it as baton slot 0 (tag 0)
//     sx[j]  = sum_i x[i,j]
//     ss0    = dot(sum_k pos_tail[k,:64], pos_head[0,:64])
// Kernel-boundary flush makes plain stores visible to the chain kernel.
// ---------------------------------------------------------------------------
__global__ __launch_bounds__(1024) void init_kernel(
    const float* __restrict__ x,
    const float* __restrict__ pos_head,
    const float* __restrict__ pos_tail)
{
    __shared__ float psum[8][D_FEAT];   // x column partials
    __shared__ float ptps[8][64];       // pos_tail column partials
    __shared__ float red[64];

    const int tid = threadIdx.x;

    // invalidate baton slots 1..63
    for (int i = tid; i < (N_WG - 1) * D_FEAT; i += 1024)
        g_chan[1 + i / D_FEAT][i % D_FEAT] = ((ull)TAG_INVALID) << 32;

    // x partials: thread (s=tid>>7, j=tid&127) sums rows s*32 .. s*32+31
    {
        const int s = tid >> 7, j = tid & 127;
        float acc = 0.f;
        #pragma unroll 8
        for (int ii = 0; ii < 32; ++ii)
            acc += x[(s * 32 + ii) * D_FEAT + j];
        psum[s][j] = acc;
    }
    // pos_tail partials: threads 0..511 -> (kb=tid>>6, d=tid&63)
    if (tid < 512) {
        const int kb = tid >> 6, d = tid & 63;
        float acc = 0.f;
        #pragma unroll 8
        for (int kk = 0; kk < 32; ++kk)
            acc += pos_tail[(kb * 32 + kk) * 64 + d];
        ptps[kb][d] = acc;
    }
    __syncthreads();

    if (tid < 64) {
        float ptd = 0.f;
        #pragma unroll
        for (int kb = 0; kb < 8; ++kb) ptd += ptps[kb][tid];
        red[tid] = ptd * pos_head[tid];   // pos_head row 0
    }
    __syncthreads();

    if (tid < 128) {
        float sx = 0.f;
        #pragma unroll
        for (int s = 0; s < 8; ++s) sx += psum[s][tid];
        float ss0 = 0.f;
        #pragma unroll
        for (int d = 0; d < 64; ++d) ss0 += red[d];
        const float v0 = ss0 * sx;
        g_chan[0][tid] = /* tag 0 */ (ull)__float_as_uint(v0);
    }
}

// ---------------------------------------------------------------------------
// Chain kernel: 64 WGs, WG g owns steps [4g, 4g+4).
// W slice (4 * 64 KB) prefetched into registers by all WGs in parallel.
// Baton: 128 lanes each poll their own packed (tag|value) entry.
// ---------------------------------------------------------------------------
__global__ __launch_bounds__(1024) void chain_kernel(
    const float* __restrict__ W,
    const float* __restrict__ a)
{
    __shared__ float v_lds[D_FEAT];
    __shared__ float psum[8][D_FEAT];

    const int g   = blockIdx.x;
    const int tid = threadIdx.x;
    const int s   = tid >> 7;      // m-block (16 rows)
    const int j   = tid & 127;     // column
    const int t0  = g * STEPS_PER_WG;

    // Prefetch W[t0..t0+3][s*16 .. s*16+15][j] into registers (64 VGPRs).
    // Issued immediately; overlaps the baton wait.
    float w[STEPS_PER_WG][16];
    #pragma unroll
    for (int k = 0; k < STEPS_PER_WG; ++k) {
        #pragma unroll
        for (int m = 0; m < 16; ++m)
            w[k][m] = W[((size_t)(t0 + k) * D_FEAT + (s * 16 + m)) * D_FEAT + j];
    }

    // Wait for the baton (v vector for step t0).
    if (tid < 128) {
        ull pk;
        for (;;) {
            pk = __hip_atomic_load(&g_chan[g][j], __ATOMIC_RELAXED,
                                   __HIP_MEMORY_SCOPE_AGENT);
            if ((unsigned)(pk >> 32) == (unsigned)g) break;
            __builtin_amdgcn_s_sleep(1);
        }
        v_lds[j] = __uint_as_float((unsigned)pk);
    }
    __syncthreads();

    #pragma unroll
    for (int k = 0; k < STEPS_PER_WG; ++k) {
        const int t = t0 + k;
        float acc = 0.f;
        #pragma unroll
        for (int m = 0; m < 16; ++m)
            acc += v_lds[s * 16 + m] * w[k][m];   // v_lds read = LDS broadcast
        psum[s][j] = acc;
        __syncthreads();

        if (tid < 128) {
            float u = 0.f;
            #pragma unroll
            for (int ss = 0; ss < 8; ++ss) u += psum[ss][j];
            g_u[t * D_FEAT + j] = u;
            const float vn = tanh_fast(a[t * N_NEUR + t + 1] * u);
            if (k < STEPS_PER_WG - 1) {
                v_lds[j] = vn;
            } else if (g + 1 < N_WG) {
                const ull pk = (((ull)(unsigned)(g + 1)) << 32) |
                               (ull)__float_as_uint(vn);
                __hip_atomic_store(&g_chan[g + 1][j], pk, __ATOMIC_RELAXED,
                                   __HIP_MEMORY_SCOPE_AGENT);
            }
        }
        __syncthreads();   // protects psum reuse + v_lds update
    }
}

// ---------------------------------------------------------------------------
// Out kernel: out[t,l,j] = tanh(a[t,l] * u[t,j]), t<256, l<1024, j<128.
// ---------------------------------------------------------------------------
__global__ __launch_bounds__(256) void out_kernel(
    const float* __restrict__ a,
    float* __restrict__ out)
{
    const long gid = (long)blockIdx.x * 256 + threadIdx.x;
    const long row = gid >> 5;            // t*1024 + l
    const int  jq  = (int)(gid & 31);
    const int  t   = (int)(row >> 10);

    const float  s  = a[row];             // a[t,l]
    const float4 u4 = ((const float4*)g_u)[t * 32 + jq];

    float4 r;
    r.x = tanh_fast(s * u4.x);
    r.y = tanh_fast(s * u4.y);
    r.z = tanh_fast(s * u4.z);
    r.w = tanh_fast(s * u4.w);

    ((float4*)out)[row * 32 + jq] = r;
}

// ---------------------------------------------------------------------------
extern "C" void kernel_launch(void* const* d_in, const int* in_sizes, int n_in,
                              void* d_out, int out_size, void* d_ws, size_t ws_size,
                              hipStream_t stream)
{
    const float* x        = (const float*)d_in[0];
    const float* pos_head = (const float*)d_in[1];
    const float* pos_tail = (const float*)d_in[2];
    const float* W        = (const float*)d_in[3];
    const float* a        = (const float*)d_in[4];
    float*       out      = (float*)d_out;

    hipLaunchKernelGGL(init_kernel, dim3(1), dim3(1024), 0, stream,
                       x, pos_head, pos_tail);

    hipLaunchKernelGGL(chain_kernel, dim3(N_WG), dim3(1024), 0, stream,
                       W, a);

    hipLaunchKernelGGL(out_kernel, dim3(32768), dim3(256), 0, stream,
                       a, out);
}

// Round 4
// 421.820 us; speedup vs baseline: 1.3931x; 1.0039x over previous
//
#include <hip/hip_runtime.h>
#include <math.h>

// Problem constants
#define D_FEAT   128
#define O_SIZE   256
#define N_NEUR   1024
#define STEPS_PER_WG 4
#define N_WG     (O_SIZE / STEPS_PER_WG)   // 64

typedef unsigned long long ull;

// Module-owned device memory (NOT d_ws — round-1 post-mortem: d_ws too small,
// OOB writes corrupted harness pristine buffers).
__device__ __align__(16) float g_u[O_SIZE * D_FEAT];
// Baton channel: (tag << 32) | float_bits(v_j) — data rides inside the atomic.
__device__ ull g_chan[N_WG][D_FEAT];

#define TAG_INVALID 0xFFFFFFFFu

// Fast, safe tanh: |err| ~1e-7, no inf/nan for any input.
__device__ __forceinline__ float tanh_fast(float x) {
    x = fminf(fmaxf(x, -20.f), 20.f);
    float e = __expf(2.f * x);
    return (e - 1.f) * __builtin_amdgcn_rcpf(e + 1.f);
}

// ---------------------------------------------------------------------------
// Init kernel (1 WG): invalidate baton slots, compute v0, publish slot 0.
// ---------------------------------------------------------------------------
__global__ __launch_bounds__(1024) void init_kernel(
    const float* __restrict__ x,
    const float* __restrict__ pos_head,
    const float* __restrict__ pos_tail)
{
    __shared__ float psum[8][D_FEAT];
    __shared__ float ptps[8][64];
    __shared__ float red[64];

    const int tid = threadIdx.x;

    for (int i = tid; i < (N_WG - 1) * D_FEAT; i += 1024)
        g_chan[1 + i / D_FEAT][i % D_FEAT] = ((ull)TAG_INVALID) << 32;

    {
        const int s = tid >> 7, j = tid & 127;
        float acc = 0.f;
        #pragma unroll 8
        for (int ii = 0; ii < 32; ++ii)
            acc += x[(s * 32 + ii) * D_FEAT + j];
        psum[s][j] = acc;
    }
    if (tid < 512) {
        const int kb = tid >> 6, d = tid & 63;
        float acc = 0.f;
        #pragma unroll 8
        for (int kk = 0; kk < 32; ++kk)
            acc += pos_tail[(kb * 32 + kk) * 64 + d];
        ptps[kb][d] = acc;
    }
    __syncthreads();

    if (tid < 64) {
        float ptd = 0.f;
        #pragma unroll
        for (int kb = 0; kb < 8; ++kb) ptd += ptps[kb][tid];
        red[tid] = ptd * pos_head[tid];   // pos_head row 0
    }
    __syncthreads();

    if (tid < 128) {
        float sx = 0.f;
        #pragma unroll
        for (int s = 0; s < 8; ++s) sx += psum[s][tid];
        float ss0 = 0.f;
        #pragma unroll
        for (int d = 0; d < 64; ++d) ss0 += red[d];
        const float v0 = ss0 * sx;
        g_chan[0][tid] = /* tag 0 */ (ull)__float_as_uint(v0);
    }
}

// ---------------------------------------------------------------------------
// Chain kernel: 64 WGs, WG g owns steps [4g, 4g+4).
// Round-3 post-mortem: VGPR_Count=44 proved the compiler SANK the W loads
// past the unbounded poll loop, putting 256 KB/WG on the serial critical
// path. Fix:
//  - waves 2..15: loads sit before __syncthreads -> cannot sink, issue at
//    kernel start, complete during the baton wait (all WGs in parallel).
//  - waves 0..1 (pollers): ds_write w to LDS scratch BEFORE polling — the
//    store consumes the loaded values, forcing the loads to complete first.
// ---------------------------------------------------------------------------
__global__ __launch_bounds__(1024) void chain_kernel(
    const float* __restrict__ W,
    const float* __restrict__ a)
{
    __shared__ float  v_lds[D_FEAT];
    __shared__ float  psum[8][D_FEAT];
    __shared__ float4 scratch[128 * 16];   // 32 KB materialization sink

    const int g   = blockIdx.x;
    const int tid = threadIdx.x;
    const int s   = tid >> 7;      // m-block (16 rows)
    const int j   = tid & 127;     // column
    const int t0  = g * STEPS_PER_WG;

    // W[t0+k][s*16+m][j] -> w[k][m]  (64 VGPRs/thread, 256 KB/WG)
    float w[STEPS_PER_WG][16];
    #pragma unroll
    for (int k = 0; k < STEPS_PER_WG; ++k) {
        #pragma unroll
        for (int m = 0; m < 16; ++m)
            w[k][m] = W[((size_t)(t0 + k) * D_FEAT + (s * 16 + m)) * D_FEAT + j];
    }

    if (tid < 128) {
        // Force materialization of the pollers' W registers before the
        // unbounded poll loop (write-only LDS sink; values stay in regs).
        #pragma unroll
        for (int k = 0; k < STEPS_PER_WG; ++k) {
            #pragma unroll
            for (int q = 0; q < 4; ++q)
                scratch[tid * 16 + k * 4 + q] =
                    make_float4(w[k][q*4+0], w[k][q*4+1], w[k][q*4+2], w[k][q*4+3]);
        }
        // Wait for the baton (v vector for step t0).
        ull pk;
        for (;;) {
            pk = __hip_atomic_load(&g_chan[g][j], __ATOMIC_RELAXED,
                                   __HIP_MEMORY_SCOPE_AGENT);
            if ((unsigned)(pk >> 32) == (unsigned)g) break;
            __builtin_amdgcn_s_sleep(1);
        }
        v_lds[j] = __uint_as_float((unsigned)pk);
    }
    __syncthreads();   // waves 2..15's W loads cannot sink past this barrier

    #pragma unroll
    for (int k = 0; k < STEPS_PER_WG; ++k) {
        const int t = t0 + k;
        float acc = 0.f;
        #pragma unroll
        for (int m = 0; m < 16; ++m)
            acc += v_lds[s * 16 + m] * w[k][m];   // v_lds read = LDS broadcast
        psum[s][j] = acc;
        __syncthreads();

        if (tid < 128) {
            float u = 0.f;
            #pragma unroll
            for (int ss = 0; ss < 8; ++ss) u += psum[ss][j];
            g_u[t * D_FEAT + j] = u;
            const float vn = tanh_fast(a[t * N_NEUR + t + 1] * u);
            if (k < STEPS_PER_WG - 1) {
                v_lds[j] = vn;
            } else if (g + 1 < N_WG) {
                const ull pk = (((ull)(unsigned)(g + 1)) << 32) |
                               (ull)__float_as_uint(vn);
                __hip_atomic_store(&g_chan[g + 1][j], pk, __ATOMIC_RELAXED,
                                   __HIP_MEMORY_SCOPE_AGENT);
            }
        }
        __syncthreads();   // protects psum reuse + v_lds update
    }
}

// ---------------------------------------------------------------------------
// Out kernel: out[t,l,j] = tanh(a[t,l] * u[t,j]), t<256, l<1024, j<128.
// ---------------------------------------------------------------------------
__global__ __launch_bounds__(256) void out_kernel(
    const float* __restrict__ a,
    float* __restrict__ out)
{
    const long gid = (long)blockIdx.x * 256 + threadIdx.x;
    const long row = gid >> 5;            // t*1024 + l
    const int  jq  = (int)(gid & 31);
    const int  t   = (int)(row >> 10);

    const float  s  = a[row];             // a[t,l]
    const float4 u4 = ((const float4*)g_u)[t * 32 + jq];

    float4 r;
    r.x = tanh_fast(s * u4.x);
    r.y = tanh_fast(s * u4.y);
    r.z = tanh_fast(s * u4.z);
    r.w = tanh_fast(s * u4.w);

    ((float4*)out)[row * 32 + jq] = r;
}

// ---------------------------------------------------------------------------
extern "C" void kernel_launch(void* const* d_in, const int* in_sizes, int n_in,
                              void* d_out, int out_size, void* d_ws, size_t ws_size,
                              hipStream_t stream)
{
    const float* x        = (const float*)d_in[0];
    const float* pos_head = (const float*)d_in[1];
    const float* pos_tail = (const float*)d_in[2];
    const float* W        = (const float*)d_in[3];
    const float* a        = (const float*)d_in[4];
    float*       out      = (float*)d_out;

    hipLaunchKernelGGL(init_kernel, dim3(1), dim3(1024), 0, stream,
                       x, pos_head, pos_tail);

    hipLaunchKernelGGL(chain_kernel, dim3(N_WG), dim3(1024), 0, stream,
                       W, a);

    hipLaunchKernelGGL(out_kernel, dim3(32768), dim3(256), 0, stream,
                       a, out);
}

// Round 6
// 403.815 us; speedup vs baseline: 1.4552x; 1.0446x over previous
//
#include <hip/hip_runtime.h>
#include <math.h>

// Problem constants
#define D_FEAT   128
#define O_SIZE   256
#define N_NEUR   1024
#define STEPS_PER_WG 4
#define N_WG     (O_SIZE / STEPS_PER_WG)   // 64

typedef unsigned long long ull;
typedef float floatx4 __attribute__((ext_vector_type(4)));   // native vec for NT store

// Module-owned device memory (NOT d_ws — round-1 post-mortem: d_ws too small,
// OOB writes corrupted harness pristine buffers).
__device__ __align__(16) float g_u[O_SIZE * D_FEAT];
// Baton channel: (tag << 32) | float_bits(v_j) — data rides inside the atomic.
__device__ ull g_chan[N_WG][D_FEAT];

#define TAG_INVALID 0xFFFFFFFFu

// Fast, safe tanh: |err| ~1e-7, no inf/nan for any input.
__device__ __forceinline__ float tanh_fast(float x) {
    x = fminf(fmaxf(x, -20.f), 20.f);
    float e = __expf(2.f * x);
    return (e - 1.f) * __builtin_amdgcn_rcpf(e + 1.f);
}

// ---------------------------------------------------------------------------
// Init kernel (1 WG): invalidate baton slots, compute v0, publish slot 0.
// ---------------------------------------------------------------------------
__global__ __launch_bounds__(1024) void init_kernel(
    const float* __restrict__ x,
    const float* __restrict__ pos_head,
    const float* __restrict__ pos_tail)
{
    __shared__ float psum[8][D_FEAT];
    __shared__ float ptps[8][64];
    __shared__ float red[64];

    const int tid = threadIdx.x;

    for (int i = tid; i < (N_WG - 1) * D_FEAT; i += 1024)
        g_chan[1 + i / D_FEAT][i % D_FEAT] = ((ull)TAG_INVALID) << 32;

    {
        const int s = tid >> 7, j = tid & 127;
        float acc = 0.f;
        #pragma unroll 8
        for (int ii = 0; ii < 32; ++ii)
            acc += x[(s * 32 + ii) * D_FEAT + j];
        psum[s][j] = acc;
    }
    if (tid < 512) {
        const int kb = tid >> 6, d = tid & 63;
        float acc = 0.f;
        #pragma unroll 8
        for (int kk = 0; kk < 32; ++kk)
            acc += pos_tail[(kb * 32 + kk) * 64 + d];
        ptps[kb][d] = acc;
    }
    __syncthreads();

    if (tid < 64) {
        float ptd = 0.f;
        #pragma unroll
        for (int kb = 0; kb < 8; ++kb) ptd += ptps[kb][tid];
        red[tid] = ptd * pos_head[tid];   // pos_head row 0
    }
    __syncthreads();

    if (tid < 128) {
        float sx = 0.f;
        #pragma unroll
        for (int s = 0; s < 8; ++s) sx += psum[s][tid];
        float ss0 = 0.f;
        #pragma unroll
        for (int d = 0; d < 64; ++d) ss0 += red[d];
        const float v0 = ss0 * sx;
        g_chan[0][tid] = /* tag 0 */ (ull)__float_as_uint(v0);
    }
}

// ---------------------------------------------------------------------------
// Chain kernel: 64 WGs, logical WG g owns steps [4g, 4g+4).
// Round-4 post-mortem: LDS scratch sink was DCE'd (LDS_Block_Size stayed
// 4608) and VGPR_Count stayed 44 -> W loads still sank past the poll loop.
// Fix: empty `asm volatile` with "+v" constraints — cannot be deleted or
// reordered across the atomic poll; forces loads to complete into live
// VGPRs BEFORE polling, so all 64 WGs stream W in parallel.
// Also: XCD-local chain swizzle — assuming round-robin bid%8 -> XCD,
// g = (bid&7)*8 + (bid>>3) keeps 56/63 handoffs inside one XCD's L2.
// ---------------------------------------------------------------------------
__global__ __launch_bounds__(1024) void chain_kernel(
    const float* __restrict__ W,
    const float* __restrict__ a)
{
    __shared__ float v_lds[D_FEAT];
    __shared__ float psum[8][D_FEAT];

    const int bid = blockIdx.x;
    const int g   = ((bid & 7) << 3) | (bid >> 3);   // XCD-local chain order
    const int tid = threadIdx.x;
    const int s   = tid >> 7;      // m-block (16 rows)
    const int j   = tid & 127;     // column
    const int t0  = g * STEPS_PER_WG;

    // W[t0+k][s*16+m][j] -> w[k][m]  (64 VGPRs/thread, 256 KB/WG)
    float w[STEPS_PER_WG][16];
    #pragma unroll
    for (int k = 0; k < STEPS_PER_WG; ++k) {
        #pragma unroll
        for (int m = 0; m < 16; ++m)
            w[k][m] = W[((size_t)(t0 + k) * D_FEAT + (s * 16 + m)) * D_FEAT + j];
    }
    // Force all 64 values live in VGPRs here (un-deletable, un-reorderable).
    #pragma unroll
    for (int k = 0; k < STEPS_PER_WG; ++k) {
        #pragma unroll
        for (int m = 0; m < 16; ++m)
            asm volatile("" : "+v"(w[k][m]));
    }

    // Wait for the baton (v vector for step t0).
    if (tid < 128) {
        ull pk;
        for (;;) {
            pk = __hip_atomic_load(&g_chan[g][j], __ATOMIC_RELAXED,
                                   __HIP_MEMORY_SCOPE_AGENT);
            if ((unsigned)(pk >> 32) == (unsigned)g) break;
            __builtin_amdgcn_s_sleep(1);
        }
        v_lds[j] = __uint_as_float((unsigned)pk);
    }
    __syncthreads();

    #pragma unroll
    for (int k = 0; k < STEPS_PER_WG; ++k) {
        const int t = t0 + k;
        float acc = 0.f;
        #pragma unroll
        for (int m = 0; m < 16; ++m)
            acc += v_lds[s * 16 + m] * w[k][m];   // v_lds read = LDS broadcast
        psum[s][j] = acc;
        __syncthreads();

        if (tid < 128) {
            float u = 0.f;
            #pragma unroll
            for (int ss = 0; ss < 8; ++ss) u += psum[ss][j];
            g_u[t * D_FEAT + j] = u;
            const float vn = tanh_fast(a[t * N_NEUR + t + 1] * u);
            if (k < STEPS_PER_WG - 1) {
                v_lds[j] = vn;
            } else if (g + 1 < N_WG) {
                const ull pk = (((ull)(unsigned)(g + 1)) << 32) |
                               (ull)__float_as_uint(vn);
                __hip_atomic_store(&g_chan[g + 1][j], pk, __ATOMIC_RELAXED,
                                   __HIP_MEMORY_SCOPE_AGENT);
            }
        }
        __syncthreads();   // protects psum reuse + v_lds update
    }
}

// ---------------------------------------------------------------------------
// Out kernel: out[t,l,j] = tanh(a[t,l] * u[t,j]), t<256, l<1024, j<128.
// Pure-write stream (134 MB) -> nontemporal stores (native ext_vector type;
// HIP's float4 class is rejected by the builtin).
// ---------------------------------------------------------------------------
__global__ __launch_bounds__(256) void out_kernel(
    const float* __restrict__ a,
    float* __restrict__ out)
{
    const long gid = (long)blockIdx.x * 256 + threadIdx.x;
    const long row = gid >> 5;            // t*1024 + l
    const int  jq  = (int)(gid & 31);
    const int  t   = (int)(row >> 10);

    const float   s  = a[row];            // a[t,l]
    const floatx4 u4 = ((const floatx4*)g_u)[t * 32 + jq];

    floatx4 r;
    r.x = tanh_fast(s * u4.x);
    r.y = tanh_fast(s * u4.y);
    r.z = tanh_fast(s * u4.z);
    r.w = tanh_fast(s * u4.w);

    __builtin_nontemporal_store(r, (floatx4*)out + row * 32 + jq);
}

// ---------------------------------------------------------------------------
extern "C" void kernel_launch(void* const* d_in, const int* in_sizes, int n_in,
                              void* d_out, int out_size, void* d_ws, size_t ws_size,
                              hipStream_t stream)
{
    const float* x        = (const float*)d_in[0];
    const float* pos_head = (const float*)d_in[1];
    const float* pos_tail = (const float*)d_in[2];
    const float* W        = (const float*)d_in[3];
    const float* a        = (const float*)d_in[4];
    float*       out      = (float*)d_out;

    hipLaunchKernelGGL(init_kernel, dim3(1), dim3(1024), 0, stream,
                       x, pos_head, pos_tail);

    hipLaunchKernelGGL(chain_kernel, dim3(N_WG), dim3(1024), 0, stream,
                       W, a);

    hipLaunchKernelGGL(out_kernel, dim3(32768), dim3(256), 0, stream,
                       a, out);
}

// Round 7
// 316.651 us; speedup vs baseline: 1.8558x; 1.2753x over previous
//
#include <hip/hip_runtime.h>
#include <math.h>

// Problem constants
#define D_FEAT   128
#define O_SIZE   256
#define N_NEUR   1024
#define STEPS_PER_WG 4
#define N_WG     (O_SIZE / STEPS_PER_WG)   // 64

typedef unsigned long long ull;
typedef float floatx4 __attribute__((ext_vector_type(4)));

// Module-owned device memory (NOT d_ws — round-1 post-mortem: d_ws too small,
// OOB writes corrupted harness pristine buffers).
__device__ __align__(16) float g_u[O_SIZE * D_FEAT];
// Baton channel: (tag << 32) | float_bits(v_j) — data rides inside the atomic.
__device__ ull g_chan[N_WG][D_FEAT];

#define TAG_INVALID 0xFFFFFFFFu

// Fast, safe tanh: |err| ~1e-7, no inf/nan for any input.
__device__ __forceinline__ float tanh_fast(float x) {
    x = fminf(fmaxf(x, -20.f), 20.f);
    float e = __expf(2.f * x);
    return (e - 1.f) * __builtin_amdgcn_rcpf(e + 1.f);
}

// ---------------------------------------------------------------------------
// Init kernel (1 WG): invalidate baton slots, compute v0, publish slot 0.
// ---------------------------------------------------------------------------
__global__ __launch_bounds__(1024) void init_kernel(
    const float* __restrict__ x,
    const float* __restrict__ pos_head,
    const float* __restrict__ pos_tail)
{
    __shared__ float psum[8][D_FEAT];
    __shared__ float ptps[8][64];
    __shared__ float red[64];

    const int tid = threadIdx.x;

    for (int i = tid; i < (N_WG - 1) * D_FEAT; i += 1024)
        g_chan[1 + i / D_FEAT][i % D_FEAT] = ((ull)TAG_INVALID) << 32;

    {
        const int s = tid >> 7, j = tid & 127;
        float acc = 0.f;
        #pragma unroll 8
        for (int ii = 0; ii < 32; ++ii)
            acc += x[(s * 32 + ii) * D_FEAT + j];
        psum[s][j] = acc;
    }
    if (tid < 512) {
        const int kb = tid >> 6, d = tid & 63;
        float acc = 0.f;
        #pragma unroll 8
        for (int kk = 0; kk < 32; ++kk)
            acc += pos_tail[(kb * 32 + kk) * 64 + d];
        ptps[kb][d] = acc;
    }
    __syncthreads();

    if (tid < 64) {
        float ptd = 0.f;
        #pragma unroll
        for (int kb = 0; kb < 8; ++kb) ptd += ptps[kb][tid];
        red[tid] = ptd * pos_head[tid];   // pos_head row 0
    }
    __syncthreads();

    if (tid < 128) {
        float sx = 0.f;
        #pragma unroll
        for (int s = 0; s < 8; ++s) sx += psum[s][tid];
        float ss0 = 0.f;
        #pragma unroll
        for (int d = 0; d < 64; ++d) ss0 += red[d];
        const float v0 = ss0 * sx;
        g_chan[0][tid] = /* tag 0 */ (ull)__float_as_uint(v0);
    }
}

// ---------------------------------------------------------------------------
// Chain kernel: 64 WGs, logical WG g owns steps [4g, 4g+4).
// Round-6 post-mortem: VGPR 56 (+12) = only the POLLERS' W loads were forced
// early; waves 2..15's loads legally sank past __syncthreads (W is read-only,
// no aliasing store -> barrier doesn't block load motion). 224µs/64 hops =
// 3.5µs = 224 KB (7/8 of the WG's W) pulled serially post-baton.
// Fix: every thread folds all 64 pinned values into a dummy accumulator that
// feeds an asm volatile sink BEFORE the poll/barrier — loads must complete
// there, in parallel across all 64 WGs at kernel start.
// ---------------------------------------------------------------------------
__global__ __launch_bounds__(1024) void chain_kernel(
    const float* __restrict__ W,
    const float* __restrict__ a)
{
    __shared__ float v_lds[D_FEAT];
    __shared__ float psum[8][D_FEAT];

    const int bid = blockIdx.x;
    const int g   = ((bid & 7) << 3) | (bid >> 3);   // XCD-local chain order
    const int tid = threadIdx.x;
    const int s   = tid >> 7;      // m-block (16 rows)
    const int j   = tid & 127;     // column
    const int t0  = g * STEPS_PER_WG;

    // W[t0+k][s*16+m][j] -> w[k][m]  (64 VGPRs/thread, 256 KB/WG)
    float w[STEPS_PER_WG][16];
    #pragma unroll
    for (int k = 0; k < STEPS_PER_WG; ++k) {
        #pragma unroll
        for (int m = 0; m < 16; ++m)
            w[k][m] = W[((size_t)(t0 + k) * D_FEAT + (s * 16 + m)) * D_FEAT + j];
    }
    // Prefetch the step scalars too.
    float ascal[STEPS_PER_WG];
    #pragma unroll
    for (int k = 0; k < STEPS_PER_WG; ++k)
        ascal[k] = a[(t0 + k) * N_NEUR + (t0 + k) + 1];

    // Force ALL loads complete into live VGPRs before any polling/barrier:
    // 1) pin each value (un-deletable, un-copyable);
    // 2) make every value a data input of one more un-deletable asm via a sum.
    float dummy = 0.f;
    #pragma unroll
    for (int k = 0; k < STEPS_PER_WG; ++k) {
        #pragma unroll
        for (int m = 0; m < 16; ++m) {
            asm volatile("" : "+v"(w[k][m]));
            dummy += w[k][m];
        }
        asm volatile("" : "+v"(ascal[k]));
    }
    asm volatile("" :: "v"(dummy));   // consumes the sum -> loads done HERE

    // Wait for the baton (v vector for step t0).
    if (tid < 128) {
        ull pk;
        for (;;) {
            pk = __hip_atomic_load(&g_chan[g][j], __ATOMIC_RELAXED,
                                   __HIP_MEMORY_SCOPE_AGENT);
            if ((unsigned)(pk >> 32) == (unsigned)g) break;
            __builtin_amdgcn_s_sleep(1);
        }
        v_lds[j] = __uint_as_float((unsigned)pk);
    }
    __syncthreads();

    #pragma unroll
    for (int k = 0; k < STEPS_PER_WG; ++k) {
        const int t = t0 + k;
        float acc = 0.f;
        #pragma unroll
        for (int m = 0; m < 16; ++m)
            acc += v_lds[s * 16 + m] * w[k][m];   // v_lds read = LDS broadcast
        psum[s][j] = acc;
        __syncthreads();

        if (tid < 128) {
            float u = 0.f;
            #pragma unroll
            for (int ss = 0; ss < 8; ++ss) u += psum[ss][j];
            g_u[t * D_FEAT + j] = u;
            const float vn = tanh_fast(ascal[k] * u);
            if (k < STEPS_PER_WG - 1) {
                v_lds[j] = vn;
            } else if (g + 1 < N_WG) {
                const ull pk = (((ull)(unsigned)(g + 1)) << 32) |
                               (ull)__float_as_uint(vn);
                __hip_atomic_store(&g_chan[g + 1][j], pk, __ATOMIC_RELAXED,
                                   __HIP_MEMORY_SCOPE_AGENT);
            }
        }
        __syncthreads();   // protects psum reuse + v_lds update
    }
}

// ---------------------------------------------------------------------------
// Out kernel: out[t,l,j] = tanh(a[t,l] * u[t,j]), t<256, l<1024, j<128.
// ---------------------------------------------------------------------------
__global__ __launch_bounds__(256) void out_kernel(
    const float* __restrict__ a,
    float* __restrict__ out)
{
    const long gid = (long)blockIdx.x * 256 + threadIdx.x;
    const long row = gid >> 5;            // t*1024 + l
    const int  jq  = (int)(gid & 31);
    const int  t   = (int)(row >> 10);

    const float   s  = a[row];            // a[t,l]
    const floatx4 u4 = ((const floatx4*)g_u)[t * 32 + jq];

    floatx4 r;
    r.x = tanh_fast(s * u4.x);
    r.y = tanh_fast(s * u4.y);
    r.z = tanh_fast(s * u4.z);
    r.w = tanh_fast(s * u4.w);

    __builtin_nontemporal_store(r, (floatx4*)out + row * 32 + jq);
}

// ---------------------------------------------------------------------------
extern "C" void kernel_launch(void* const* d_in, const int* in_sizes, int n_in,
                              void* d_out, int out_size, void* d_ws, size_t ws_size,
                              hipStream_t stream)
{
    const float* x        = (const float*)d_in[0];
    const float* pos_head = (const float*)d_in[1];
    const float* pos_tail = (const float*)d_in[2];
    const float* W        = (const float*)d_in[3];
    const float* a        = (const float*)d_in[4];
    float*       out      = (float*)d_out;

    hipLaunchKernelGGL(init_kernel, dim3(1), dim3(1024), 0, stream,
                       x, pos_head, pos_tail);

    hipLaunchKernelGGL(chain_kernel, dim3(N_WG), dim3(1024), 0, stream,
                       W, a);

    hipLaunchKernelGGL(out_kernel, dim3(32768), dim3(256), 0, stream,
                       a, out);
}